// Round 13
// baseline (598.567 us; speedup 1.0000x reference)
//
#include <hip/hip_runtime.h>
#include <hip/hip_bf16.h>

// SelfAttention, folded + mask-compacted + m97-structure attention GEMMs:
//   E = Qc@xk^T (+w32[k]); P' = exp(E/32 + w32); out = (P'@value')*rowinv + cv
//   value' = value@(Wfc@Wv)^T ; masked rows = colmean(value') + cv
// gemm128c: 128x128 tile, BK=32, 32KB LDS double-buffer, 256 thr, 5 blocks/CU.

#define DEVINL __device__ __forceinline__

typedef __bf16 bf16x8 __attribute__((ext_vector_type(8)));
typedef float f32x4 __attribute__((ext_vector_type(4)));

static constexpr int Bb = 8;
static constexpr int S = 2048;
static constexpr int D = 1024;

DEVINL unsigned short f32_to_bf16(float f) {
  unsigned u = __float_as_uint(f);
  u = (u + 0x7FFFu + ((u >> 16) & 1u)) >> 16;
  return (unsigned short)u;
}
DEVINL float bflo(unsigned u) { return __uint_as_float(u << 16); }
DEVINL float bfhi(unsigned u) { return __uint_as_float(u & 0xFFFF0000u); }

DEVINL void gload16(const unsigned short* g, char* l) {
  __builtin_amdgcn_global_load_lds((__attribute__((address_space(1))) void*)g,
                                   (__attribute__((address_space(3))) void*)l,
                                   16, 0, 0);
}
DEVINL void gload16u(const unsigned short* g, unsigned short* l) {
  gload16(g, (char*)l);
}

#define BAR() __builtin_amdgcn_s_barrier()
#define LGK0() asm volatile("s_waitcnt lgkmcnt(0)" ::: "memory")

#define PH_OPEN() \
  BAR();          \
  LGK0();         \
  __builtin_amdgcn_s_setprio(1)
#define PH_CLOSE()               \
  __builtin_amdgcn_s_setprio(0); \
  BAR()

#define MFMA_QUAD(A_, B_, MO, NO)                                              \
  {                                                                            \
    _Pragma("unroll") for (int mi_ = 0; mi_ < 4; mi_++) {                      \
      _Pragma("unroll") for (int nj_ = 0; nj_ < 2; nj_++) {                    \
        acc[(MO) + mi_][(NO) + nj_] = __builtin_amdgcn_mfma_f32_16x16x32_bf16( \
            A_[mi_][0], B_[nj_][0], acc[(MO) + mi_][(NO) + nj_], 0, 0, 0);     \
        acc[(MO) + mi_][(NO) + nj_] = __builtin_amdgcn_mfma_f32_16x16x32_bf16( \
            A_[mi_][1], B_[nj_][1], acc[(MO) + mi_][(NO) + nj_], 0, 0, 0);     \
      }                                                                        \
    }                                                                          \
  }

// ---------------- f32 -> bf16 conversion -----------------------------------
__global__ __launch_bounds__(256) void conv_f32_bf16(const float* __restrict__ in,
                                                     unsigned short* __restrict__ out,
                                                     int n8) {
  int i = blockIdx.x * 256 + threadIdx.x;
  int stride = gridDim.x * 256;
  for (; i < n8; i += stride) {
    const float4* p = (const float4*)in + (size_t)i * 2;
    float4 a = p[0], b = p[1];
    uint4 o;
    o.x = (unsigned)f32_to_bf16(a.x) | ((unsigned)f32_to_bf16(a.y) << 16);
    o.y = (unsigned)f32_to_bf16(a.z) | ((unsigned)f32_to_bf16(a.w) << 16);
    o.z = (unsigned)f32_to_bf16(b.x) | ((unsigned)f32_to_bf16(b.y) << 16);
    o.w = (unsigned)f32_to_bf16(b.z) | ((unsigned)f32_to_bf16(b.w) << 16);
    ((uint4*)out)[i] = o;
  }
}

// ---------------- fused: bf16(key_) + w32[row] = xkB[row,:].g32 ------------
__global__ __launch_bounds__(256) void conv_k_wvec(const float* __restrict__ in,
                                                   const float* __restrict__ g32,
                                                   unsigned short* __restrict__ xkB,
                                                   float* __restrict__ w32) {
  const int row = blockIdx.x * 4 + (threadIdx.x >> 6);
  const int lane = threadIdx.x & 63;
  const float* src = in + (size_t)row * 1024 + lane * 16;
  unsigned short* dst = xkB + (size_t)row * 1024 + lane * 16;
  float s = 0.f;
  uint4 o[2];
  unsigned* po = (unsigned*)o;
#pragma unroll
  for (int c = 0; c < 4; c++) {
    float4 v = *(const float4*)(src + c * 4);
    float4 g = *(const float4*)(g32 + lane * 16 + c * 4);
    unsigned lo = (unsigned)f32_to_bf16(v.x) | ((unsigned)f32_to_bf16(v.y) << 16);
    unsigned hi = (unsigned)f32_to_bf16(v.z) | ((unsigned)f32_to_bf16(v.w) << 16);
    po[c * 2] = lo;
    po[c * 2 + 1] = hi;
    s += bflo(lo) * g.x + bfhi(lo) * g.y + bflo(hi) * g.z + bfhi(hi) * g.w;
  }
  *(uint4*)dst = o[0];
  *(uint4*)(dst + 8) = o[1];
#pragma unroll
  for (int off = 32; off >= 1; off >>= 1) s += __shfl_xor(s, off);
  if (lane == 0) w32[row] = s;
}

// ---------------- transposed conv: f32 [R][C] -> bf16 [C][R] (weights) -----
__global__ __launch_bounds__(256) void tconv(const float* __restrict__ in,
                                             unsigned short* __restrict__ out,
                                             int R, int C) {
  __shared__ unsigned short t[64][72];
  const int c0 = blockIdx.x * 64, r0 = blockIdx.y * 64, b = blockIdx.z;
  in += (size_t)b * R * C;
  out += (size_t)b * R * C;
  const int tr = threadIdx.x >> 4;
  const int tc = threadIdx.x & 15;
#pragma unroll
  for (int i = 0; i < 4; i++) {
    int row = tr + i * 16;
    float4 v = *(const float4*)(in + (size_t)(r0 + row) * C + c0 + tc * 4);
    t[tc * 4 + 0][row] = f32_to_bf16(v.x);
    t[tc * 4 + 1][row] = f32_to_bf16(v.y);
    t[tc * 4 + 2][row] = f32_to_bf16(v.z);
    t[tc * 4 + 3][row] = f32_to_bf16(v.w);
  }
  __syncthreads();
  const int c = threadIdx.x >> 2, rs = (threadIdx.x & 3) * 16;
  unsigned short tmp[16];
#pragma unroll
  for (int j = 0; j < 16; j++) tmp[j] = t[c][rs + j];
  *(uint4*)(out + (size_t)(c0 + c) * R + r0 + rs) = *(const uint4*)&tmp[0];
  *(uint4*)(out + (size_t)(c0 + c) * R + r0 + rs + 8) = *(const uint4*)&tmp[8];
}

// ---------------- cv[f] = Wfc[f,:].bv + bfc[f] -----------------------------
__global__ __launch_bounds__(256) void cvec_kernel(const float* __restrict__ Wfc,
                                                   const float* __restrict__ bv,
                                                   const float* __restrict__ bfc,
                                                   float* __restrict__ cv) {
  const int f = blockIdx.x;
  const float* row = Wfc + (size_t)f * 1024;
  float s = 0.f;
  for (int e = threadIdx.x; e < 1024; e += 256) s += row[e] * bv[e];
#pragma unroll
  for (int off = 32; off >= 1; off >>= 1) s += __shfl_xor(s, off);
  __shared__ float red[4];
  const int wave = threadIdx.x >> 6, lane = threadIdx.x & 63;
  if (lane == 0) red[wave] = s;
  __syncthreads();
  if (threadIdx.x == 0) cv[f] = red[0] + red[1] + red[2] + red[3] + bfc[f];
}

// ---------------- g32[e] = (WkT[e,:].bq)/32 --------------------------------
__global__ __launch_bounds__(256) void gvec_kernel(const unsigned short* __restrict__ WkT,
                                                   const float* __restrict__ bq,
                                                   float* __restrict__ g32) {
  const int e = blockIdx.x;
  const unsigned short* row = WkT + (size_t)e * 1024;
  const int j0 = threadIdx.x * 4;
  uint2 v = *(const uint2*)(row + j0);
  float4 b4 = *(const float4*)(bq + j0);
  float s = bflo(v.x) * b4.x + bfhi(v.x) * b4.y + bflo(v.y) * b4.z + bfhi(v.y) * b4.w;
#pragma unroll
  for (int off = 32; off >= 1; off >>= 1) s += __shfl_xor(s, off);
  __shared__ float red[4];
  const int wave = threadIdx.x >> 6, lane = threadIdx.x & 63;
  if (lane == 0) red[wave] = s;
  __syncthreads();
  if (threadIdx.x == 0) g32[e] = (red[0] + red[1] + red[2] + red[3]) * (1.0f / 32.0f);
}

// ---------------- mask scan: per-batch compaction lists --------------------
// cnts layout: [0..7]=cnt, [8..15]=cntp128, [16..23]=cntp256, [24..31]=mcnt
__global__ __launch_bounds__(256) void mask_scan(const int* __restrict__ msk,
                                                 int* __restrict__ qidx,
                                                 int* __restrict__ midx,
                                                 int* __restrict__ cnts) {
  __shared__ int offs[257];
  const int b = blockIdx.x;
  const int* mrow = msk + b * 2048;
  const int base = threadIdx.x * 8;
  int m[8], c = 0;
#pragma unroll
  for (int i = 0; i < 8; i++) {
    m[i] = mrow[base + i];
    c += m[i];
  }
  offs[threadIdx.x + 1] = c;
  __syncthreads();
  if (threadIdx.x == 0) {
    offs[0] = 0;
    for (int j = 1; j <= 256; j++) offs[j] += offs[j - 1];
    int tot = offs[256];
    cnts[b] = tot;
    cnts[8 + b] = (tot + 127) & ~127;
    cnts[16 + b] = (tot + 255) & ~255;
    cnts[24 + b] = 2048 - tot;
  }
  __syncthreads();
  int u = offs[threadIdx.x];
#pragma unroll
  for (int i = 0; i < 8; i++) {
    int idx = base + i;
    if (m[i])
      qidx[b * 2048 + (u++)] = idx;
    else
      midx[b * 2048 + (idx - u)] = idx;
  }
}

// ---------------- compact query rows (gather + f32->bf16, zero-pad) --------
__global__ __launch_bounds__(128) void compact_q(const float* __restrict__ q,
                                                 const int* __restrict__ qidx,
                                                 const int* __restrict__ cnts,
                                                 unsigned short* __restrict__ xqC) {
  const int r = blockIdx.x;
  const int b = r >> 11, i = r & 2047;
  if (i >= cnts[16 + b]) return;
  unsigned short* dst = xqC + ((size_t)b * 2048 + i) * 1024;
  if (i < cnts[b]) {
    const float* src = q + ((size_t)b * 2048 + qidx[b * 2048 + i]) * 1024 + threadIdx.x * 8;
    float4 a = *(const float4*)src;
    float4 c = *(const float4*)(src + 4);
    uint4 o;
    o.x = (unsigned)f32_to_bf16(a.x) | ((unsigned)f32_to_bf16(a.y) << 16);
    o.y = (unsigned)f32_to_bf16(a.z) | ((unsigned)f32_to_bf16(a.w) << 16);
    o.z = (unsigned)f32_to_bf16(c.x) | ((unsigned)f32_to_bf16(c.y) << 16);
    o.w = (unsigned)f32_to_bf16(c.z) | ((unsigned)f32_to_bf16(c.w) << 16);
    ((uint4*)dst)[threadIdx.x] = o;
  } else {
    ((uint4*)dst)[threadIdx.x] = make_uint4(0, 0, 0, 0);
  }
}

// ---------------- colmeanPcv[b][f] = mean_s value'[b][s][f] + cv[f] --------
__global__ __launch_bounds__(64) void colmean_kernel(const unsigned short* __restrict__ vpT,
                                                     const float* __restrict__ cv,
                                                     float* __restrict__ cm) {
  const int f = blockIdx.x, b = blockIdx.y;
  const unsigned short* base = vpT + (size_t)f * 16384 + b * 2048 + threadIdx.x * 32;
  float s = 0.f;
#pragma unroll
  for (int c = 0; c < 4; c++) {
    uint4 v = ((const uint4*)base)[c];
    unsigned u[4] = {v.x, v.y, v.z, v.w};
#pragma unroll
    for (int i = 0; i < 4; i++) s += bflo(u[i]) + bfhi(u[i]);
  }
#pragma unroll
  for (int off = 32; off >= 1; off >>= 1) s += __shfl_xor(s, off);
  if (threadIdx.x == 0) cm[b * 1024 + f] = s * (1.0f / 2048.0f) + cv[f];
}

// ---------------- fill masked output rows ----------------------------------
__global__ __launch_bounds__(128) void fill_masked(const int* __restrict__ midx,
                                                   const int* __restrict__ cnts,
                                                   const float* __restrict__ cm,
                                                   float* __restrict__ out) {
  const int r = blockIdx.x;
  const int b = r >> 11, j = r & 2047;
  if (j >= cnts[24 + b]) return;
  const int qr = midx[b * 2048 + j];
  float* dst = out + ((size_t)b * 2048 + qr) * 1024 + threadIdx.x * 8;
  const float* src = cm + b * 1024 + threadIdx.x * 8;
  *(float4*)dst = *(const float4*)src;
  *(float4*)(dst + 4) = *(const float4*)(src + 4);
}

// ---------------- rowinv[r] = 1 / sum_{c<32} partialT[c][r] ----------------
__global__ __launch_bounds__(256) void rowinv_kernel(const float* __restrict__ partialT,
                                                     float* __restrict__ rowinv) {
  const int r = blockIdx.x * 256 + threadIdx.x;
  float s = 0.f;
#pragma unroll
  for (int c = 0; c < 32; c++) s += partialT[(size_t)c * 16384 + r];
  rowinv[r] = 1.0f / s;
}

// ---------------- batched 128x128 GEMM (weight-sized) ----------------------
__global__ __launch_bounds__(256) void gemm128(const unsigned short* __restrict__ A,
                                               const unsigned short* __restrict__ Bt,
                                               unsigned short* __restrict__ C,
                                               int M, int N, int K,
                                               long long bsA, long long bsB, long long bsC) {
  const int tid = threadIdx.x;
  const int wave = tid >> 6;
  const int lane = tid & 63;
  const int wr = wave >> 1, wc = wave & 1;
  const int m0 = blockIdx.y * 128, n0 = blockIdx.x * 128;
  A += (size_t)blockIdx.z * bsA;
  Bt += (size_t)blockIdx.z * bsB;
  C += (size_t)blockIdx.z * bsC;

  __shared__ unsigned short lds[2][2][128 * 32];

  const int srow = wave * 16 + (lane >> 2);
  const int scol = (lane & 3) * 8;
  const unsigned short* gA = A + (size_t)(m0 + srow) * K + scol;
  const unsigned short* gB = Bt + (size_t)(n0 + srow) * K + scol;

  f32x4 acc[4][4];
#pragma unroll
  for (int i = 0; i < 4; i++)
#pragma unroll
    for (int j = 0; j < 4; j++) acc[i][j] = (f32x4){0.f, 0.f, 0.f, 0.f};

  const int nk = K >> 5;
  auto stage = [&](int buf, int kt) {
    const unsigned short* a0 = gA + (size_t)kt * 32;
    const unsigned short* b0 = gB + (size_t)kt * 32;
    unsigned short* la = &lds[buf][0][wave * 512];
    unsigned short* lb = &lds[buf][1][wave * 512];
    gload16u(a0, la);
    gload16u(a0 + (size_t)64 * K, la + 2048);
    gload16u(b0, lb);
    gload16u(b0 + (size_t)64 * K, lb + 2048);
  };

  stage(0, 0);
  asm volatile("s_waitcnt vmcnt(0)" ::: "memory");
  __syncthreads();

  const int fm = lane & 15;
  const int fk = (lane >> 4) * 8;

  int cur = 0;
  for (int t = 0; t < nk; ++t) {
    if (t + 1 < nk) stage(cur ^ 1, t + 1);
    bf16x8 af[4], bfr[4];
#pragma unroll
    for (int i = 0; i < 4; i++)
      af[i] = *(const bf16x8*)&lds[cur][0][(wr * 64 + i * 16 + fm) * 32 + fk];
#pragma unroll
    for (int j = 0; j < 4; j++)
      bfr[j] = *(const bf16x8*)&lds[cur][1][(wc * 64 + j * 16 + fm) * 32 + fk];
#pragma unroll
    for (int i = 0; i < 4; i++)
#pragma unroll
      for (int j = 0; j < 4; j++)
        acc[i][j] = __builtin_amdgcn_mfma_f32_16x16x32_bf16(af[i], bfr[j], acc[i][j], 0, 0, 0);
    asm volatile("s_waitcnt vmcnt(0)" ::: "memory");
    __syncthreads();
    cur ^= 1;
  }

  const int en = n0 + wc * 64 + fm;
  const int em = m0 + wr * 64 + ((lane >> 4) << 2);
#pragma unroll
  for (int j = 0; j < 4; j++)
#pragma unroll
    for (int i = 0; i < 4; i++)
#pragma unroll
      for (int r = 0; r < 4; r++)
        C[(size_t)(em + i * 16 + r) * N + en + j * 16] = f32_to_bf16(acc[i][j][r]);
}

// ---------------- gemm128c: m97-structure co-resident kernel ---------------
// 128x128 tile, BK=32, 32KB LDS, 256 thr (2x2 waves), 5 blocks/CU.
// OUTMODE 3 (E): A=keys, B=compacted queries; P'=exp(acc*scale+w32[key]);
//   partialT rowsums; LDS-transposed E[q][k] stores; exit if n0>=cntp128.
// OUTMODE 6 (PV): A=E slots, B=vpT; out[qidx[row]][col]=acc*rowinv[row]+cv[col];
//   exit if m0>=cntp128.
template <int OUTMODE>
__global__ __launch_bounds__(256, 5) void gemm128c(
    const unsigned short* __restrict__ A, const unsigned short* __restrict__ Bt,
    const float* __restrict__ aux,   // mode3: w32 ; mode6: rowinv
    const float* __restrict__ bias,  // mode6: cv
    const int* __restrict__ cnts, const int* __restrict__ qidx,
    float* __restrict__ partialT, void* __restrict__ Cv,
    int N, int K, int lda, int ldb,
    long long bsA, long long bsB, long long bsC, float scale) {
  __shared__ unsigned short lds[2][2][128 * 32];  // 32 KB
  char* smem = (char*)&lds[0][0][0];
  const int tid = threadIdx.x;
  const int wave = tid >> 6, lane = tid & 63;
  const int wm = wave >> 1, wn = wave & 1;  // 2(M) x 2(N)

  const int gx = gridDim.x, gy = gridDim.y;
  const int nwg = gx * gy * (int)gridDim.z;
  const int wg = blockIdx.x + gx * (blockIdx.y + gy * blockIdx.z);
  const int swz = (wg & 7) * (nwg >> 3) + (wg >> 3);
  const int bx = swz % gx;
  const int rem = swz / gx;
  const int by = rem % gy;
  const int bz = rem / gy;

  const int m0 = by * 128, n0 = bx * 128;
  if (OUTMODE == 3) {
    if (n0 >= cnts[8 + bz]) return;
  } else {
    if (m0 >= cnts[8 + bz]) return;
  }
  A += (size_t)bz * bsA;
  Bt += (size_t)bz * bsB;

  const int srow = wave * 16 + (lane >> 2);
  const int scol = (lane & 3) * 8;
  const unsigned short* gA = A + (size_t)(m0 + srow) * lda + scol;
  const unsigned short* gB = Bt + (size_t)(n0 + srow) * ldb + scol;

  f32x4 acc[4][4];
#pragma unroll
  for (int i = 0; i < 4; i++)
#pragma unroll
    for (int j = 0; j < 4; j++) acc[i][j] = (f32x4){0.f, 0.f, 0.f, 0.f};

  const int nk = K >> 5;
  auto stage = [&](int buf, int kt) {
    const unsigned short* a0 = gA + (size_t)kt * 32;
    const unsigned short* b0 = gB + (size_t)kt * 32;
    unsigned short* la = &lds[buf][0][wave * 512];
    unsigned short* lb = &lds[buf][1][wave * 512];
    gload16u(a0, la);
    gload16u(a0 + (size_t)64 * lda, la + 2048);
    gload16u(b0, lb);
    gload16u(b0 + (size_t)64 * ldb, lb + 2048);
  };

  stage(0, 0);
  asm volatile("s_waitcnt vmcnt(0)" ::: "memory");
  __syncthreads();

  const int fm = lane & 15;
  const int fk = (lane >> 4) * 8;

  int cur = 0;
  for (int t = 0; t < nk; ++t) {
    if (t + 1 < nk) stage(cur ^ 1, t + 1);
    bf16x8 af[4], bfr[4];
#pragma unroll
    for (int i = 0; i < 4; i++)
      af[i] = *(const bf16x8*)&lds[cur][0][(wm * 64 + i * 16 + fm) * 32 + fk];
#pragma unroll
    for (int j = 0; j < 4; j++)
      bfr[j] = *(const bf16x8*)&lds[cur][1][(wn * 64 + j * 16 + fm) * 32 + fk];
    __builtin_amdgcn_s_setprio(1);
#pragma unroll
    for (int i = 0; i < 4; i++)
#pragma unroll
      for (int j = 0; j < 4; j++)
        acc[i][j] = __builtin_amdgcn_mfma_f32_16x16x32_bf16(af[i], bfr[j], acc[i][j], 0, 0, 0);
    __builtin_amdgcn_s_setprio(0);
    asm volatile("s_waitcnt vmcnt(0)" ::: "memory");
    __syncthreads();
    cur ^= 1;
  }

  const int fr = lane & 15;
  const int fg = lane >> 4;

  if (OUTMODE == 3) {
    // P' epilogue: keys = A-rows (w32 per key), queries = B-cols
    const int keyrow0 = m0 + wm * 64 + fg * 4;  // + mi*16
    const int colq = wn * 64 + fr;              // + nj*16
    float psum[4] = {0.f, 0.f, 0.f, 0.f};
#pragma unroll
    for (int mi = 0; mi < 4; mi++) {
      const float4 w4 = *(const float4*)&aux[bz * 2048 + keyrow0 + mi * 16];
      const int lrow = wm * 64 + fg * 4 + mi * 16;
#pragma unroll
      for (int nj = 0; nj < 4; nj++) {
        float p0 = __expf(fmaf(acc[mi][nj][0], scale, w4.x));
        float p1 = __expf(fmaf(acc[mi][nj][1], scale, w4.y));
        float p2 = __expf(fmaf(acc[mi][nj][2], scale, w4.z));
        float p3 = __expf(fmaf(acc[mi][nj][3], scale, w4.w));
        psum[nj] += (p0 + p1) + (p2 + p3);
        unsigned lo = (unsigned)f32_to_bf16(p0) | ((unsigned)f32_to_bf16(p1) << 16);
        unsigned hi = (unsigned)f32_to_bf16(p2) | ((unsigned)f32_to_bf16(p3) << 16);
        const int c = colq + nj * 16;
        const int byte = c * 256 + ((((lrow >> 3) ^ (c & 7)) << 4) | ((lrow & 4) << 1));
        *(uint2*)(smem + byte) = make_uint2(lo, hi);
      }
    }
#pragma unroll
    for (int nj = 0; nj < 4; nj++) {
      psum[nj] += __shfl_xor(psum[nj], 16);
      psum[nj] += __shfl_xor(psum[nj], 32);
    }
    if (fg == 0) {
#pragma unroll
      for (int nj = 0; nj < 4; nj++)
        partialT[(size_t)(by * 2 + wm) * 16384 + bz * 2048 + n0 + colq + nj * 16] = psum[nj];
    }
    __syncthreads();
    // readback: 8 q-rows per pass (half-wave each), 16 passes; 8B/lane
    unsigned short* Eb = (unsigned short*)Cv + (size_t)bz * bsC;
    const int qh = wave * 2 + (lane >> 5);
    const int kq = (lane & 31) * 4;
#pragma unroll
    for (int p = 0; p < 16; p++) {
      const int ql = qh + p * 8;
      const int byte = ql * 256 + ((((kq >> 3) ^ (ql & 7)) << 4) | ((kq & 4) << 1));
      uint2 vv = *(const uint2*)(smem + byte);
      *(uint2*)(Eb + (size_t)(n0 + ql) * 2048 + m0 + kq) = vv;
    }
  } else {
    // PV epilogue: out[qidx[row]][col] = acc*rowinv[row] + cv[col]
    float* C = (float*)Cv + (size_t)bz * bsC;
    const int* qx = qidx + bz * 2048;
    const int cb = cnts[bz];
    const int row0base = m0 + wm * 64 + fg * 4;
    const int colbase = n0 + wn * 64 + fr;
#pragma unroll
    for (int mi = 0; mi < 4; mi++) {
      const int j0 = row0base + mi * 16;
      const float4 ri = *(const float4*)&aux[bz * 2048 + j0];
      int qr[4];
      bool ok[4];
#pragma unroll
      for (int r = 0; r < 4; r++) {
        ok[r] = (j0 + r) < cb;
        qr[r] = ok[r] ? qx[j0 + r] : 0;
      }
#pragma unroll
      for (int nj = 0; nj < 4; nj++) {
        const int col = colbase + nj * 16;
        const float cvv = bias[col];
        if (ok[0]) C[(size_t)qr[0] * N + col] = fmaf(acc[mi][nj][0], ri.x, cvv);
        if (ok[1]) C[(size_t)qr[1] * N + col] = fmaf(acc[mi][nj][1], ri.y, cvv);
        if (ok[2]) C[(size_t)qr[2] * N + col] = fmaf(acc[mi][nj][2], ri.z, cvv);
        if (ok[3]) C[(size_t)qr[3] * N + col] = fmaf(acc[mi][nj][3], ri.w, cvv);
      }
    }
  }
}

// ---------------- 256x256 GEMM (Qc / vpT): mode 1 swapped bf16 -------------
// exitmode: 0 none; 1 exit if (n0&2047) >= cnts[16 + (n0>>11)]
template <int OUTMODE, bool HAS_BIAS, int EXITMODE>
__global__ __launch_bounds__(512, 2) void gemm256(
    const unsigned short* __restrict__ A, const unsigned short* __restrict__ Bt,
    const float* __restrict__ bias, const int* __restrict__ cnts,
    const int* __restrict__ qidx, float* __restrict__ partial,
    void* __restrict__ Cv, int M, int N, int K, int lda, int ldb,
    long long bsA, long long bsB, long long bsC, float scale) {
  extern __shared__ char smem[];  // 128 KB
  const int tid = threadIdx.x;
  const int wave = tid >> 6, lane = tid & 63;
  const int wr = wave >> 2, wc = wave & 3;

  const int gx = gridDim.x, gy = gridDim.y;
  const int nwg = gx * gy * (int)gridDim.z;
  const int wg = blockIdx.x + gx * (blockIdx.y + gy * blockIdx.z);
  const int swz = (wg & 7) * (nwg >> 3) + (wg >> 3);
  const int bx = swz % gx;
  const int rem = swz / gx;
  const int by = rem % gy;
  const int bz = rem / gy;

  const int m0 = by * 256, n0 = bx * 256;
  if (EXITMODE == 1) {
    if ((n0 & 2047) >= cnts[16 + (n0 >> 11)]) return;
  }
  A += (size_t)bz * bsA;
  Bt += (size_t)bz * bsB;

  const int rl = lane >> 3;
  const int gl = (lane & 7) ^ rl;
  const unsigned short* gA = A + (size_t)(m0 + wave * 8 + rl) * lda + gl * 8;
  const unsigned short* gB = Bt + (size_t)(n0 + wave * 8 + rl) * ldb + gl * 8;

  auto stageA = [&](int db, int t, int h) {
    const unsigned short* g = gA + (size_t)(h * 128) * lda + (size_t)t * 64;
    char* l = smem + db * 65536 + h * 16384 + wave * 1024;
    gload16(g, l);
    gload16(g + (size_t)64 * lda, l + 8192);
  };
  auto stageB = [&](int db, int t, int h) {
    const unsigned short* g = gB + (size_t)(h * 128) * ldb + (size_t)t * 64;
    char* l = smem + db * 65536 + 32768 + h * 16384 + wave * 1024;
    gload16(g, l);
    gload16(g + (size_t)64 * ldb, l + 8192);
  };

  const int fr = lane & 15;
  const int fg = lane >> 4;
  auto readA = [&](int db, int mi, int kc) -> bf16x8 {
    const int row = wr * 128 + mi * 16 + fr;
    const int g = (kc * 4 + fg) ^ (row & 7);
    return *(const bf16x8*)(smem + db * 65536 + row * 128 + g * 16);
  };
  auto readB = [&](int db, int nj, int kc) -> bf16x8 {
    const int row = wc * 64 + nj * 16 + fr;
    const int g = (kc * 4 + fg) ^ (row & 7);
    return *(const bf16x8*)(smem + db * 65536 + 32768 + row * 128 + g * 16);
  };

  f32x4 acc[8][4];
#pragma unroll
  for (int i = 0; i < 8; i++)
#pragma unroll
    for (int j = 0; j < 4; j++) acc[i][j] = (f32x4){0.f, 0.f, 0.f, 0.f};

  stageA(0, 0, 0);
  stageA(0, 0, 1);
  stageB(0, 0, 0);
  stageB(0, 0, 1);
  stageB(1, 1, 0);
  stageB(1, 1, 1);
  asm volatile("s_waitcnt vmcnt(4)" ::: "memory");
  BAR();

  const int nt = K >> 6;
  const int niter = nt >> 1;

  for (int j = 0; j < niter; ++j) {
    const int t0 = 2 * j, t1 = 2 * j + 1;
    const bool more = (j + 1 < niter);
    bf16x8 a[4][2], b0[2][2], b1[2][2];

#pragma unroll
    for (int mi = 0; mi < 4; mi++) { a[mi][0] = readA(0, mi, 0); a[mi][1] = readA(0, mi, 1); }
#pragma unroll
    for (int nj = 0; nj < 2; nj++) { b0[nj][0] = readB(0, nj, 0); b0[nj][1] = readB(0, nj, 1); }
    stageA(1, t1, 0);
    asm volatile("s_waitcnt lgkmcnt(8)" ::: "memory");
    PH_OPEN();
    MFMA_QUAD(a, b0, 0, 0);
    PH_CLOSE();

#pragma unroll
    for (int nj = 0; nj < 2; nj++) { b1[nj][0] = readB(0, nj + 2, 0); b1[nj][1] = readB(0, nj + 2, 1); }
    stageA(1, t1, 1);
    PH_OPEN();
    MFMA_QUAD(a, b1, 0, 2);
    PH_CLOSE();

#pragma unroll
    for (int mi = 0; mi < 4; mi++) { a[mi][0] = readA(0, mi + 4, 0); a[mi][1] = readA(0, mi + 4, 1); }
    if (more) stageB(0, t0 + 2, 0);
    PH_OPEN();
    MFMA_QUAD(a, b0, 4, 0);
    PH_CLOSE();

    if (more) stageB(0, t0 + 2, 1);
    BAR();
    __builtin_amdgcn_s_setprio(1);
    MFMA_QUAD(a, b1, 4, 2);
    __builtin_amdgcn_s_setprio(0);
    if (more)
      asm volatile("s_waitcnt vmcnt(4)" ::: "memory");
    else
      asm volatile("s_waitcnt vmcnt(0)" ::: "memory");
    BAR();

#pragma unroll
    for (int mi = 0; mi < 4; mi++) { a[mi][0] = readA(1, mi, 0); a[mi][1] = readA(1, mi, 1); }
#pragma unroll
    for (int nj = 0; nj < 2; nj++) { b0[nj][0] = readB(1, nj, 0); b0[nj][1] = readB(1, nj, 1); }
    if (more) stageA(0, t0 + 2, 0);
    asm volatile("s_waitcnt lgkmcnt(8)" ::: "memory");
    PH_OPEN();
    MFMA_QUAD(a, b0, 0, 0);
    PH_CLOSE();

#pragma unroll
    for (int nj = 0; nj < 2; nj++) { b1[nj][0] = readB(1, nj + 2, 0); b1[nj][1] = readB(1, nj + 2, 1); }
    if (more) stageA(0, t0 + 2, 1);
    PH_OPEN();
    MFMA_QUAD(a, b1, 0, 2);
    PH_CLOSE();

#pragma unroll
    for (int mi = 0; mi < 4; mi++) { a[mi][0] = readA(1, mi + 4, 0); a[mi][1] = readA(1, mi + 4, 1); }
    if (more) stageB(1, t1 + 2, 0);
    PH_OPEN();
    MFMA_QUAD(a, b0, 4, 0);
    PH_CLOSE();

    if (more) stageB(1, t1 + 2, 1);
    BAR();
    __builtin_amdgcn_s_setprio(1);
    MFMA_QUAD(a, b1, 4, 2);
    __builtin_amdgcn_s_setprio(0);
    asm volatile("s_waitcnt vmcnt(4)" ::: "memory");
    BAR();
  }

  const int row0base = m0 + wr * 128 + fg * 4;

  // OUTMODE 1: LDS-transposed bf16 stores OUT[bcol][arow]
  {
    const int lcol = wc * 64 + fr;
    const int lrow0 = wr * 128 + fg * 4;
#pragma unroll
    for (int mi = 0; mi < 8; mi++) {
      const int lrow = lrow0 + mi * 16;
      float4 bw = make_float4(0.f, 0.f, 0.f, 0.f);
      if (HAS_BIAS) bw = *(const float4*)&bias[row0base + mi * 16];
#pragma unroll
      for (int nj = 0; nj < 4; nj++) {
        float v0 = acc[mi][nj][0] + bw.x;
        float v1 = acc[mi][nj][1] + bw.y;
        float v2 = acc[mi][nj][2] + bw.z;
        float v3 = acc[mi][nj][3] + bw.w;
        unsigned lo = (unsigned)f32_to_bf16(v0) | ((unsigned)f32_to_bf16(v1) << 16);
        unsigned hi = (unsigned)f32_to_bf16(v2) | ((unsigned)f32_to_bf16(v3) << 16);
        const int c = lcol + nj * 16;
        const int byte = c * 512 + ((((lrow >> 3) ^ (c & 7)) << 4) | ((lrow & 4) << 1));
        *(uint2*)(smem + byte) = make_uint2(lo, hi);
      }
    }
    __syncthreads();
    unsigned short* C = (unsigned short*)Cv + (size_t)bz * bsC;
    const int qh = wave * 2 + (lane >> 5);
    const int kl = (lane & 31) * 8;
#pragma unroll
    for (int p = 0; p < 16; p++) {
      const int ql = qh + p * 16;
      const int byte = ql * 512 + ((((kl >> 3) ^ (ql & 7)) << 4));
      uint4 vv = *(const uint4*)(smem + byte);
      *(uint4*)(C + (size_t)(n0 + ql) * M + m0 + kl) = vv;
    }
  }
}

// ---------------------------------------------------------------------------
extern "C" void kernel_launch(void* const* d_in, const int* in_sizes, int n_in,
                              void* d_out, int out_size, void* d_ws, size_t ws_size,
                              hipStream_t stream) {
  const float* q = (const float*)d_in[0];
  const float* k_ = (const float*)d_in[1];
  const float* v = (const float*)d_in[2];
  const int* msk = (const int*)d_in[3];
  const float* Wq = (const float*)d_in[4];
  const float* bq = (const float*)d_in[5];
  const float* Wk = (const float*)d_in[6];
  const float* Wv = (const float*)d_in[8];
  const float* bv = (const float*)d_in[9];
  const float* Wfc = (const float*)d_in[10];
  const float* bfc = (const float*)d_in[11];

  char* ws = (char*)d_ws;
  const size_t MB = 1u << 20;
  const size_t KB = 1u << 10;
  unsigned short* WkT = (unsigned short*)(ws + 0 * MB);
  unsigned short* WfcB = (unsigned short*)(ws + 2 * MB);
  unsigned short* WqT = (unsigned short*)(ws + 4 * MB);
  unsigned short* WvT = (unsigned short*)(ws + 6 * MB);
  unsigned short* Mt = (unsigned short*)(ws + 8 * MB);
  unsigned short* W2 = (unsigned short*)(ws + 10 * MB);
  float* partialT = (float*)(ws + 12 * MB);                 // 2 MB [32][16384]
  float* rowinv = (float*)(ws + 14 * MB);                   // 64 KB
  float* cv = (float*)(ws + 14 * MB + 64 * KB);
  float* g32 = (float*)(ws + 14 * MB + 128 * KB);
  float* w32 = (float*)(ws + 14 * MB + 192 * KB);           // 64 KB
  int* qidx = (int*)(ws + 14 * MB + 256 * KB);              // 64 KB
  int* midx = (int*)(ws + 14 * MB + 320 * KB);              // 64 KB
  int* cnts = (int*)(ws + 14 * MB + 384 * KB);              // 128 B
  float* cm = (float*)(ws + 14 * MB + 512 * KB);            // 32 KB
  unsigned short* Qc = (unsigned short*)(ws + 16 * MB);     // 32 MB
  unsigned short* xkB = (unsigned short*)(ws + 48 * MB);    // 32 MB
  unsigned short* vpT = (unsigned short*)(ws + 80 * MB);    // 32 MB [f][bs]
  unsigned short* xqC = (unsigned short*)(ws + 112 * MB);   // 32 MB compacted
  unsigned short* vB = (unsigned short*)(ws + 144 * MB);    // 32 MB
  unsigned short* E = (unsigned short*)(ws + 112 * MB);     // 64 MB (alias)

  const int NBS = Bb * S * D;

  auto conv = [&](const float* in, unsigned short* out, int n) {
    int n8 = n / 8;
    int blocks = (n8 + 255) / 256;
    if (blocks > 2048) blocks = 2048;
    conv_f32_bf16<<<dim3(blocks), dim3(256), 0, stream>>>(in, out, n8);
  };

  // ---- weight preprocessing
  tconv<<<dim3(16, 16, 1), dim3(256), 0, stream>>>(Wq, WqT, D, D);
  tconv<<<dim3(16, 16, 1), dim3(256), 0, stream>>>(Wk, WkT, D, D);
  conv(Wfc, WfcB, D * D);
  tconv<<<dim3(16, 16, 1), dim3(256), 0, stream>>>(Wv, WvT, D, D);
  gemm128<<<dim3(8, 8, 2), dim3(256), 0, stream>>>(
      WkT, WqT, Mt, D, D, D, (long long)D * D, (long long)D * D, (long long)D * D);
  cvec_kernel<<<dim3(1024), dim3(256), 0, stream>>>(Wfc, bv, bfc, cv);
  gvec_kernel<<<dim3(1024), dim3(256), 0, stream>>>(WkT, bq, g32);

  // ---- mask compaction
  mask_scan<<<dim3(8), dim3(256), 0, stream>>>(msk, qidx, midx, cnts);
  compact_q<<<dim3(16384), dim3(128), 0, stream>>>(q, qidx, cnts, xqC);

  const float invscale = 1.0f / 32.0f;

  // ---- Qc = xqC @ M : swapped (A=Mt, B=xqC) -> Qc[slot][f], exit on N
  gemm256<1, false, 1><<<dim3(64, 4, 1), dim3(512), 131072, stream>>>(
      Mt, xqC, nullptr, cnts, nullptr, nullptr, Qc, D, Bb * S, D, D, D,
      0, 0, 0, 1.0f);
  // ---- xkB = bf16(key_) + w32 in one pass
  conv_k_wvec<<<dim3(4096), dim3(256), 0, stream>>>(k_, g32, xkB, w32);
  // ---- vpT = (value @ W2^T)^T
  conv(v, vB, NBS);
  gemm256<1, false, 0><<<dim3(4, 64, 1), dim3(512), 131072, stream>>>(
      vB, W2, nullptr, nullptr, nullptr, nullptr, vpT, Bb * S, D, D, D, D,
      0, 0, 0, 1.0f);
  // ---- colmean of value' (+cv) for masked rows
  colmean_kernel<<<dim3(1024, 8), dim3(64), 0, stream>>>(vpT, cv, cm);
  // ---- E = exp(Qc.xk/32 + w32): 128x128 m97-structure, exit on query tiles
  gemm128c<3><<<dim3(16, 16, 8), dim3(256), 0, stream>>>(
      xkB, Qc, w32, nullptr, cnts, nullptr, partialT, E,
      D, 1024, 1024, 1024, (long long)S * D, (long long)S * D,
      (long long)S * S, invscale);
  // ---- rowinv
  rowinv_kernel<<<dim3(64), dim3(256), 0, stream>>>(partialT, rowinv);
  // ---- out(unmasked) = (P' @ value')*rowinv + cv: 128x128, exit on slot tiles
  gemm128c<6><<<dim3(8, 16, 8), dim3(256), 0, stream>>>(
      E, vpT, rowinv, cv, cnts, qidx, nullptr, d_out,
      D, 2048, 2048, Bb * S, (long long)S * S, (long long)S,
      (long long)S * D, 1.0f);
  // ---- out(masked) = colmean + cv
  fill_masked<<<dim3(16384), dim3(128), 0, stream>>>(midx, cnts, cm, (float*)d_out);
}

// Round 14
// 296.825 us; speedup vs baseline: 2.0166x; 2.0166x over previous
//
#include <hip/hip_runtime.h>
#include <hip/hip_bf16.h>

// SelfAttention, folded + mask-compacted + m97-structure attention GEMMs:
//   E = Qc@xk^T (+w32[k]); P' = exp(E/32 + w32); out = (P'@value')*rowinv + cv
//   value' = value@(Wfc@Wv)^T ; masked rows = colmean(value') + cv
// gemm128c: 128x128 tile, BK=32, 32KB LDS double-buffer, 256 thr, 3 blocks/CU.
// NOTE: (256,5) launch bound spills acc to scratch (VGPR 60->48, WRITE 224MB) —
// keep (256,3).

#define DEVINL __device__ __forceinline__

typedef __bf16 bf16x8 __attribute__((ext_vector_type(8)));
typedef float f32x4 __attribute__((ext_vector_type(4)));

static constexpr int Bb = 8;
static constexpr int S = 2048;
static constexpr int D = 1024;

DEVINL unsigned short f32_to_bf16(float f) {
  unsigned u = __float_as_uint(f);
  u = (u + 0x7FFFu + ((u >> 16) & 1u)) >> 16;
  return (unsigned short)u;
}
DEVINL float bflo(unsigned u) { return __uint_as_float(u << 16); }
DEVINL float bfhi(unsigned u) { return __uint_as_float(u & 0xFFFF0000u); }

DEVINL void gload16(const unsigned short* g, char* l) {
  __builtin_amdgcn_global_load_lds((__attribute__((address_space(1))) void*)g,
                                   (__attribute__((address_space(3))) void*)l,
                                   16, 0, 0);
}
DEVINL void gload16u(const unsigned short* g, unsigned short* l) {
  gload16(g, (char*)l);
}

#define BAR() __builtin_amdgcn_s_barrier()
#define LGK0() asm volatile("s_waitcnt lgkmcnt(0)" ::: "memory")

#define PH_OPEN() \
  BAR();          \
  LGK0();         \
  __builtin_amdgcn_s_setprio(1)
#define PH_CLOSE()               \
  __builtin_amdgcn_s_setprio(0); \
  BAR()

#define MFMA_QUAD(A_, B_, MO, NO)                                              \
  {                                                                            \
    _Pragma("unroll") for (int mi_ = 0; mi_ < 4; mi_++) {                      \
      _Pragma("unroll") for (int nj_ = 0; nj_ < 2; nj_++) {                    \
        acc[(MO) + mi_][(NO) + nj_] = __builtin_amdgcn_mfma_f32_16x16x32_bf16( \
            A_[mi_][0], B_[nj_][0], acc[(MO) + mi_][(NO) + nj_], 0, 0, 0);     \
        acc[(MO) + mi_][(NO) + nj_] = __builtin_amdgcn_mfma_f32_16x16x32_bf16( \
            A_[mi_][1], B_[nj_][1], acc[(MO) + mi_][(NO) + nj_], 0, 0, 0);     \
      }                                                                        \
    }                                                                          \
  }

// ---------------- f32 -> bf16 conversion -----------------------------------
__global__ __launch_bounds__(256) void conv_f32_bf16(const float* __restrict__ in,
                                                     unsigned short* __restrict__ out,
                                                     int n8) {
  int i = blockIdx.x * 256 + threadIdx.x;
  int stride = gridDim.x * 256;
  for (; i < n8; i += stride) {
    const float4* p = (const float4*)in + (size_t)i * 2;
    float4 a = p[0], b = p[1];
    uint4 o;
    o.x = (unsigned)f32_to_bf16(a.x) | ((unsigned)f32_to_bf16(a.y) << 16);
    o.y = (unsigned)f32_to_bf16(a.z) | ((unsigned)f32_to_bf16(a.w) << 16);
    o.z = (unsigned)f32_to_bf16(b.x) | ((unsigned)f32_to_bf16(b.y) << 16);
    o.w = (unsigned)f32_to_bf16(b.z) | ((unsigned)f32_to_bf16(b.w) << 16);
    ((uint4*)out)[i] = o;
  }
}

// ---------------- fused: bf16(key_) + w32[row] = xkB[row,:].g32 ------------
__global__ __launch_bounds__(256) void conv_k_wvec(const float* __restrict__ in,
                                                   const float* __restrict__ g32,
                                                   unsigned short* __restrict__ xkB,
                                                   float* __restrict__ w32) {
  const int row = blockIdx.x * 4 + (threadIdx.x >> 6);
  const int lane = threadIdx.x & 63;
  const float* src = in + (size_t)row * 1024 + lane * 16;
  unsigned short* dst = xkB + (size_t)row * 1024 + lane * 16;
  float s = 0.f;
  uint4 o[2];
  unsigned* po = (unsigned*)o;
#pragma unroll
  for (int c = 0; c < 4; c++) {
    float4 v = *(const float4*)(src + c * 4);
    float4 g = *(const float4*)(g32 + lane * 16 + c * 4);
    unsigned lo = (unsigned)f32_to_bf16(v.x) | ((unsigned)f32_to_bf16(v.y) << 16);
    unsigned hi = (unsigned)f32_to_bf16(v.z) | ((unsigned)f32_to_bf16(v.w) << 16);
    po[c * 2] = lo;
    po[c * 2 + 1] = hi;
    s += bflo(lo) * g.x + bfhi(lo) * g.y + bflo(hi) * g.z + bfhi(hi) * g.w;
  }
  *(uint4*)dst = o[0];
  *(uint4*)(dst + 8) = o[1];
#pragma unroll
  for (int off = 32; off >= 1; off >>= 1) s += __shfl_xor(s, off);
  if (lane == 0) w32[row] = s;
}

// ---------------- transposed conv: f32 [R][C] -> bf16 [C][R] (weights) -----
__global__ __launch_bounds__(256) void tconv(const float* __restrict__ in,
                                             unsigned short* __restrict__ out,
                                             int R, int C) {
  __shared__ unsigned short t[64][72];
  const int c0 = blockIdx.x * 64, r0 = blockIdx.y * 64, b = blockIdx.z;
  in += (size_t)b * R * C;
  out += (size_t)b * R * C;
  const int tr = threadIdx.x >> 4;
  const int tc = threadIdx.x & 15;
#pragma unroll
  for (int i = 0; i < 4; i++) {
    int row = tr + i * 16;
    float4 v = *(const float4*)(in + (size_t)(r0 + row) * C + c0 + tc * 4);
    t[tc * 4 + 0][row] = f32_to_bf16(v.x);
    t[tc * 4 + 1][row] = f32_to_bf16(v.y);
    t[tc * 4 + 2][row] = f32_to_bf16(v.z);
    t[tc * 4 + 3][row] = f32_to_bf16(v.w);
  }
  __syncthreads();
  const int c = threadIdx.x >> 2, rs = (threadIdx.x & 3) * 16;
  unsigned short tmp[16];
#pragma unroll
  for (int j = 0; j < 16; j++) tmp[j] = t[c][rs + j];
  *(uint4*)(out + (size_t)(c0 + c) * R + r0 + rs) = *(const uint4*)&tmp[0];
  *(uint4*)(out + (size_t)(c0 + c) * R + r0 + rs + 8) = *(const uint4*)&tmp[8];
}

// ---------------- cv[f] = Wfc[f,:].bv + bfc[f] -----------------------------
__global__ __launch_bounds__(256) void cvec_kernel(const float* __restrict__ Wfc,
                                                   const float* __restrict__ bv,
                                                   const float* __restrict__ bfc,
                                                   float* __restrict__ cv) {
  const int f = blockIdx.x;
  const float* row = Wfc + (size_t)f * 1024;
  float s = 0.f;
  for (int e = threadIdx.x; e < 1024; e += 256) s += row[e] * bv[e];
#pragma unroll
  for (int off = 32; off >= 1; off >>= 1) s += __shfl_xor(s, off);
  __shared__ float red[4];
  const int wave = threadIdx.x >> 6, lane = threadIdx.x & 63;
  if (lane == 0) red[wave] = s;
  __syncthreads();
  if (threadIdx.x == 0) cv[f] = red[0] + red[1] + red[2] + red[3] + bfc[f];
}

// ---------------- g32[e] = (WkT[e,:].bq)/32 --------------------------------
__global__ __launch_bounds__(256) void gvec_kernel(const unsigned short* __restrict__ WkT,
                                                   const float* __restrict__ bq,
                                                   float* __restrict__ g32) {
  const int e = blockIdx.x;
  const unsigned short* row = WkT + (size_t)e * 1024;
  const int j0 = threadIdx.x * 4;
  uint2 v = *(const uint2*)(row + j0);
  float4 b4 = *(const float4*)(bq + j0);
  float s = bflo(v.x) * b4.x + bfhi(v.x) * b4.y + bflo(v.y) * b4.z + bfhi(v.y) * b4.w;
#pragma unroll
  for (int off = 32; off >= 1; off >>= 1) s += __shfl_xor(s, off);
  __shared__ float red[4];
  const int wave = threadIdx.x >> 6, lane = threadIdx.x & 63;
  if (lane == 0) red[wave] = s;
  __syncthreads();
  if (threadIdx.x == 0) g32[e] = (red[0] + red[1] + red[2] + red[3]) * (1.0f / 32.0f);
}

// ---------------- mask scan: per-batch compaction lists --------------------
// cnts layout: [0..7]=cnt, [8..15]=cntp128, [16..23]=cntp256, [24..31]=mcnt
__global__ __launch_bounds__(256) void mask_scan(const int* __restrict__ msk,
                                                 int* __restrict__ qidx,
                                                 int* __restrict__ midx,
                                                 int* __restrict__ cnts) {
  __shared__ int offs[257];
  const int b = blockIdx.x;
  const int* mrow = msk + b * 2048;
  const int base = threadIdx.x * 8;
  int m[8], c = 0;
#pragma unroll
  for (int i = 0; i < 8; i++) {
    m[i] = mrow[base + i];
    c += m[i];
  }
  offs[threadIdx.x + 1] = c;
  __syncthreads();
  if (threadIdx.x == 0) {
    offs[0] = 0;
    for (int j = 1; j <= 256; j++) offs[j] += offs[j - 1];
    int tot = offs[256];
    cnts[b] = tot;
    cnts[8 + b] = (tot + 127) & ~127;
    cnts[16 + b] = (tot + 255) & ~255;
    cnts[24 + b] = 2048 - tot;
  }
  __syncthreads();
  int u = offs[threadIdx.x];
#pragma unroll
  for (int i = 0; i < 8; i++) {
    int idx = base + i;
    if (m[i])
      qidx[b * 2048 + (u++)] = idx;
    else
      midx[b * 2048 + (idx - u)] = idx;
  }
}

// ---------------- compact query rows (gather + f32->bf16, zero-pad) --------
__global__ __launch_bounds__(128) void compact_q(const float* __restrict__ q,
                                                 const int* __restrict__ qidx,
                                                 const int* __restrict__ cnts,
                                                 unsigned short* __restrict__ xqC) {
  const int r = blockIdx.x;
  const int b = r >> 11, i = r & 2047;
  if (i >= cnts[16 + b]) return;
  unsigned short* dst = xqC + ((size_t)b * 2048 + i) * 1024;
  if (i < cnts[b]) {
    const float* src = q + ((size_t)b * 2048 + qidx[b * 2048 + i]) * 1024 + threadIdx.x * 8;
    float4 a = *(const float4*)src;
    float4 c = *(const float4*)(src + 4);
    uint4 o;
    o.x = (unsigned)f32_to_bf16(a.x) | ((unsigned)f32_to_bf16(a.y) << 16);
    o.y = (unsigned)f32_to_bf16(a.z) | ((unsigned)f32_to_bf16(a.w) << 16);
    o.z = (unsigned)f32_to_bf16(c.x) | ((unsigned)f32_to_bf16(c.y) << 16);
    o.w = (unsigned)f32_to_bf16(c.z) | ((unsigned)f32_to_bf16(c.w) << 16);
    ((uint4*)dst)[threadIdx.x] = o;
  } else {
    ((uint4*)dst)[threadIdx.x] = make_uint4(0, 0, 0, 0);
  }
}

// ---------------- colmeanPcv[b][f] = mean_s value'[b][s][f] + cv[f] --------
__global__ __launch_bounds__(64) void colmean_kernel(const unsigned short* __restrict__ vpT,
                                                     const float* __restrict__ cv,
                                                     float* __restrict__ cm) {
  const int f = blockIdx.x, b = blockIdx.y;
  const unsigned short* base = vpT + (size_t)f * 16384 + b * 2048 + threadIdx.x * 32;
  float s = 0.f;
#pragma unroll
  for (int c = 0; c < 4; c++) {
    uint4 v = ((const uint4*)base)[c];
    unsigned u[4] = {v.x, v.y, v.z, v.w};
#pragma unroll
    for (int i = 0; i < 4; i++) s += bflo(u[i]) + bfhi(u[i]);
  }
#pragma unroll
  for (int off = 32; off >= 1; off >>= 1) s += __shfl_xor(s, off);
  if (threadIdx.x == 0) cm[b * 1024 + f] = s * (1.0f / 2048.0f) + cv[f];
}

// ---------------- fill masked output rows ----------------------------------
__global__ __launch_bounds__(128) void fill_masked(const int* __restrict__ midx,
                                                   const int* __restrict__ cnts,
                                                   const float* __restrict__ cm,
                                                   float* __restrict__ out) {
  const int r = blockIdx.x;
  const int b = r >> 11, j = r & 2047;
  if (j >= cnts[24 + b]) return;
  const int qr = midx[b * 2048 + j];
  float* dst = out + ((size_t)b * 2048 + qr) * 1024 + threadIdx.x * 8;
  const float* src = cm + b * 1024 + threadIdx.x * 8;
  *(float4*)dst = *(const float4*)src;
  *(float4*)(dst + 4) = *(const float4*)(src + 4);
}

// ---------------- rowinv[r] = 1 / sum_{c<32} partialT[c][r] ----------------
__global__ __launch_bounds__(256) void rowinv_kernel(const float* __restrict__ partialT,
                                                     float* __restrict__ rowinv) {
  const int r = blockIdx.x * 256 + threadIdx.x;
  float s = 0.f;
#pragma unroll
  for (int c = 0; c < 32; c++) s += partialT[(size_t)c * 16384 + r];
  rowinv[r] = 1.0f / s;
}

// ---------------- batched 128x128 GEMM (weight-sized) ----------------------
__global__ __launch_bounds__(256) void gemm128(const unsigned short* __restrict__ A,
                                               const unsigned short* __restrict__ Bt,
                                               unsigned short* __restrict__ C,
                                               int M, int N, int K,
                                               long long bsA, long long bsB, long long bsC) {
  const int tid = threadIdx.x;
  const int wave = tid >> 6;
  const int lane = tid & 63;
  const int wr = wave >> 1, wc = wave & 1;
  const int m0 = blockIdx.y * 128, n0 = blockIdx.x * 128;
  A += (size_t)blockIdx.z * bsA;
  Bt += (size_t)blockIdx.z * bsB;
  C += (size_t)blockIdx.z * bsC;

  __shared__ unsigned short lds[2][2][128 * 32];

  const int srow = wave * 16 + (lane >> 2);
  const int scol = (lane & 3) * 8;
  const unsigned short* gA = A + (size_t)(m0 + srow) * K + scol;
  const unsigned short* gB = Bt + (size_t)(n0 + srow) * K + scol;

  f32x4 acc[4][4];
#pragma unroll
  for (int i = 0; i < 4; i++)
#pragma unroll
    for (int j = 0; j < 4; j++) acc[i][j] = (f32x4){0.f, 0.f, 0.f, 0.f};

  const int nk = K >> 5;
  auto stage = [&](int buf, int kt) {
    const unsigned short* a0 = gA + (size_t)kt * 32;
    const unsigned short* b0 = gB + (size_t)kt * 32;
    unsigned short* la = &lds[buf][0][wave * 512];
    unsigned short* lb = &lds[buf][1][wave * 512];
    gload16u(a0, la);
    gload16u(a0 + (size_t)64 * K, la + 2048);
    gload16u(b0, lb);
    gload16u(b0 + (size_t)64 * K, lb + 2048);
  };

  stage(0, 0);
  asm volatile("s_waitcnt vmcnt(0)" ::: "memory");
  __syncthreads();

  const int fm = lane & 15;
  const int fk = (lane >> 4) * 8;

  int cur = 0;
  for (int t = 0; t < nk; ++t) {
    if (t + 1 < nk) stage(cur ^ 1, t + 1);
    bf16x8 af[4], bfr[4];
#pragma unroll
    for (int i = 0; i < 4; i++)
      af[i] = *(const bf16x8*)&lds[cur][0][(wr * 64 + i * 16 + fm) * 32 + fk];
#pragma unroll
    for (int j = 0; j < 4; j++)
      bfr[j] = *(const bf16x8*)&lds[cur][1][(wc * 64 + j * 16 + fm) * 32 + fk];
#pragma unroll
    for (int i = 0; i < 4; i++)
#pragma unroll
      for (int j = 0; j < 4; j++)
        acc[i][j] = __builtin_amdgcn_mfma_f32_16x16x32_bf16(af[i], bfr[j], acc[i][j], 0, 0, 0);
    asm volatile("s_waitcnt vmcnt(0)" ::: "memory");
    __syncthreads();
    cur ^= 1;
  }

  const int en = n0 + wc * 64 + fm;
  const int em = m0 + wr * 64 + ((lane >> 4) << 2);
#pragma unroll
  for (int j = 0; j < 4; j++)
#pragma unroll
    for (int i = 0; i < 4; i++)
#pragma unroll
      for (int r = 0; r < 4; r++)
        C[(size_t)(em + i * 16 + r) * N + en + j * 16] = f32_to_bf16(acc[i][j][r]);
}

// ---------------- gemm128c: m97-structure co-resident kernel ---------------
// 128x128 tile, BK=32, 32KB LDS, 256 thr (2x2 waves), 3 blocks/CU.
// OUTMODE 3 (E): A=keys, B=compacted queries; P'=exp(acc*scale+w32[key]);
//   partialT rowsums; LDS-transposed E[q][k] stores; exit if n0>=cntp128.
// OUTMODE 6 (PV): A=E slots, B=vpT; out[qidx[row]][col]=acc*rowinv[row]+cv[col];
//   exit if m0>=cntp128.
template <int OUTMODE>
__global__ __launch_bounds__(256, 3) void gemm128c(
    const unsigned short* __restrict__ A, const unsigned short* __restrict__ Bt,
    const float* __restrict__ aux,   // mode3: w32 ; mode6: rowinv
    const float* __restrict__ bias,  // mode6: cv
    const int* __restrict__ cnts, const int* __restrict__ qidx,
    float* __restrict__ partialT, void* __restrict__ Cv,
    int N, int K, int lda, int ldb,
    long long bsA, long long bsB, long long bsC, float scale) {
  __shared__ unsigned short lds[2][2][128 * 32];  // 32 KB
  char* smem = (char*)&lds[0][0][0];
  const int tid = threadIdx.x;
  const int wave = tid >> 6, lane = tid & 63;
  const int wm = wave >> 1, wn = wave & 1;  // 2(M) x 2(N)

  const int gx = gridDim.x, gy = gridDim.y;
  const int nwg = gx * gy * (int)gridDim.z;
  const int wg = blockIdx.x + gx * (blockIdx.y + gy * blockIdx.z);
  const int swz = (wg & 7) * (nwg >> 3) + (wg >> 3);
  const int bx = swz % gx;
  const int rem = swz / gx;
  const int by = rem % gy;
  const int bz = rem / gy;

  const int m0 = by * 128, n0 = bx * 128;
  if (OUTMODE == 3) {
    if (n0 >= cnts[8 + bz]) return;
  } else {
    if (m0 >= cnts[8 + bz]) return;
  }
  A += (size_t)bz * bsA;
  Bt += (size_t)bz * bsB;

  const int srow = wave * 16 + (lane >> 2);
  const int scol = (lane & 3) * 8;
  const unsigned short* gA = A + (size_t)(m0 + srow) * lda + scol;
  const unsigned short* gB = Bt + (size_t)(n0 + srow) * ldb + scol;

  f32x4 acc[4][4];
#pragma unroll
  for (int i = 0; i < 4; i++)
#pragma unroll
    for (int j = 0; j < 4; j++) acc[i][j] = (f32x4){0.f, 0.f, 0.f, 0.f};

  const int nk = K >> 5;
  auto stage = [&](int buf, int kt) {
    const unsigned short* a0 = gA + (size_t)kt * 32;
    const unsigned short* b0 = gB + (size_t)kt * 32;
    unsigned short* la = &lds[buf][0][wave * 512];
    unsigned short* lb = &lds[buf][1][wave * 512];
    gload16u(a0, la);
    gload16u(a0 + (size_t)64 * lda, la + 2048);
    gload16u(b0, lb);
    gload16u(b0 + (size_t)64 * ldb, lb + 2048);
  };

  stage(0, 0);
  asm volatile("s_waitcnt vmcnt(0)" ::: "memory");
  __syncthreads();

  const int fm = lane & 15;
  const int fk = (lane >> 4) * 8;

  int cur = 0;
  for (int t = 0; t < nk; ++t) {
    if (t + 1 < nk) stage(cur ^ 1, t + 1);
    bf16x8 af[4], bfr[4];
#pragma unroll
    for (int i = 0; i < 4; i++)
      af[i] = *(const bf16x8*)&lds[cur][0][(wm * 64 + i * 16 + fm) * 32 + fk];
#pragma unroll
    for (int j = 0; j < 4; j++)
      bfr[j] = *(const bf16x8*)&lds[cur][1][(wn * 64 + j * 16 + fm) * 32 + fk];
    __builtin_amdgcn_s_setprio(1);
#pragma unroll
    for (int i = 0; i < 4; i++)
#pragma unroll
      for (int j = 0; j < 4; j++)
        acc[i][j] = __builtin_amdgcn_mfma_f32_16x16x32_bf16(af[i], bfr[j], acc[i][j], 0, 0, 0);
    __builtin_amdgcn_s_setprio(0);
    asm volatile("s_waitcnt vmcnt(0)" ::: "memory");
    __syncthreads();
    cur ^= 1;
  }

  const int fr = lane & 15;
  const int fg = lane >> 4;

  if (OUTMODE == 3) {
    // P' epilogue: keys = A-rows (w32 per key), queries = B-cols
    const int keyrow0 = m0 + wm * 64 + fg * 4;  // + mi*16
    const int colq = wn * 64 + fr;              // + nj*16
    float psum[4] = {0.f, 0.f, 0.f, 0.f};
#pragma unroll
    for (int mi = 0; mi < 4; mi++) {
      const float4 w4 = *(const float4*)&aux[bz * 2048 + keyrow0 + mi * 16];
      const int lrow = wm * 64 + fg * 4 + mi * 16;
#pragma unroll
      for (int nj = 0; nj < 4; nj++) {
        float p0 = __expf(fmaf(acc[mi][nj][0], scale, w4.x));
        float p1 = __expf(fmaf(acc[mi][nj][1], scale, w4.y));
        float p2 = __expf(fmaf(acc[mi][nj][2], scale, w4.z));
        float p3 = __expf(fmaf(acc[mi][nj][3], scale, w4.w));
        psum[nj] += (p0 + p1) + (p2 + p3);
        unsigned lo = (unsigned)f32_to_bf16(p0) | ((unsigned)f32_to_bf16(p1) << 16);
        unsigned hi = (unsigned)f32_to_bf16(p2) | ((unsigned)f32_to_bf16(p3) << 16);
        const int c = colq + nj * 16;
        const int byte = c * 256 + ((((lrow >> 3) ^ (c & 7)) << 4) | ((lrow & 4) << 1));
        *(uint2*)(smem + byte) = make_uint2(lo, hi);
      }
    }
#pragma unroll
    for (int nj = 0; nj < 4; nj++) {
      psum[nj] += __shfl_xor(psum[nj], 16);
      psum[nj] += __shfl_xor(psum[nj], 32);
    }
    if (fg == 0) {
#pragma unroll
      for (int nj = 0; nj < 4; nj++)
        partialT[(size_t)(by * 2 + wm) * 16384 + bz * 2048 + n0 + colq + nj * 16] = psum[nj];
    }
    __syncthreads();
    // readback: 8 q-rows per pass (half-wave each), 16 passes; 8B/lane
    unsigned short* Eb = (unsigned short*)Cv + (size_t)bz * bsC;
    const int qh = wave * 2 + (lane >> 5);
    const int kq = (lane & 31) * 4;
#pragma unroll
    for (int p = 0; p < 16; p++) {
      const int ql = qh + p * 8;
      const int byte = ql * 256 + ((((kq >> 3) ^ (ql & 7)) << 4) | ((kq & 4) << 1));
      uint2 vv = *(const uint2*)(smem + byte);
      *(uint2*)(Eb + (size_t)(n0 + ql) * 2048 + m0 + kq) = vv;
    }
  } else {
    // PV epilogue: out[qidx[row]][col] = acc*rowinv[row] + cv[col]
    float* C = (float*)Cv + (size_t)bz * bsC;
    const int* qx = qidx + bz * 2048;
    const int cb = cnts[bz];
    const int row0base = m0 + wm * 64 + fg * 4;
    const int colbase = n0 + wn * 64 + fr;
#pragma unroll
    for (int mi = 0; mi < 4; mi++) {
      const int j0 = row0base + mi * 16;
      const float4 ri = *(const float4*)&aux[bz * 2048 + j0];
      int qr[4];
      bool ok[4];
#pragma unroll
      for (int r = 0; r < 4; r++) {
        ok[r] = (j0 + r) < cb;
        qr[r] = ok[r] ? qx[j0 + r] : 0;
      }
#pragma unroll
      for (int nj = 0; nj < 4; nj++) {
        const int col = colbase + nj * 16;
        const float cvv = bias[col];
        if (ok[0]) C[(size_t)qr[0] * N + col] = fmaf(acc[mi][nj][0], ri.x, cvv);
        if (ok[1]) C[(size_t)qr[1] * N + col] = fmaf(acc[mi][nj][1], ri.y, cvv);
        if (ok[2]) C[(size_t)qr[2] * N + col] = fmaf(acc[mi][nj][2], ri.z, cvv);
        if (ok[3]) C[(size_t)qr[3] * N + col] = fmaf(acc[mi][nj][3], ri.w, cvv);
      }
    }
  }
}

// ---------------- 256x256 GEMM (Qc / vpT): mode 1 swapped bf16 -------------
// exitmode: 0 none; 1 exit if (n0&2047) >= cnts[16 + (n0>>11)]
template <int OUTMODE, bool HAS_BIAS, int EXITMODE>
__global__ __launch_bounds__(512, 2) void gemm256(
    const unsigned short* __restrict__ A, const unsigned short* __restrict__ Bt,
    const float* __restrict__ bias, const int* __restrict__ cnts,
    const int* __restrict__ qidx, float* __restrict__ partial,
    void* __restrict__ Cv, int M, int N, int K, int lda, int ldb,
    long long bsA, long long bsB, long long bsC, float scale) {
  extern __shared__ char smem[];  // 128 KB
  const int tid = threadIdx.x;
  const int wave = tid >> 6, lane = tid & 63;
  const int wr = wave >> 2, wc = wave & 3;

  const int gx = gridDim.x, gy = gridDim.y;
  const int nwg = gx * gy * (int)gridDim.z;
  const int wg = blockIdx.x + gx * (blockIdx.y + gy * blockIdx.z);
  const int swz = (wg & 7) * (nwg >> 3) + (wg >> 3);
  const int bx = swz % gx;
  const int rem = swz / gx;
  const int by = rem % gy;
  const int bz = rem / gy;

  const int m0 = by * 256, n0 = bx * 256;
  if (EXITMODE == 1) {
    if ((n0 & 2047) >= cnts[16 + (n0 >> 11)]) return;
  }
  A += (size_t)bz * bsA;
  Bt += (size_t)bz * bsB;

  const int rl = lane >> 3;
  const int gl = (lane & 7) ^ rl;
  const unsigned short* gA = A + (size_t)(m0 + wave * 8 + rl) * lda + gl * 8;
  const unsigned short* gB = Bt + (size_t)(n0 + wave * 8 + rl) * ldb + gl * 8;

  auto stageA = [&](int db, int t, int h) {
    const unsigned short* g = gA + (size_t)(h * 128) * lda + (size_t)t * 64;
    char* l = smem + db * 65536 + h * 16384 + wave * 1024;
    gload16(g, l);
    gload16(g + (size_t)64 * lda, l + 8192);
  };
  auto stageB = [&](int db, int t, int h) {
    const unsigned short* g = gB + (size_t)(h * 128) * ldb + (size_t)t * 64;
    char* l = smem + db * 65536 + 32768 + h * 16384 + wave * 1024;
    gload16(g, l);
    gload16(g + (size_t)64 * ldb, l + 8192);
  };

  const int fr = lane & 15;
  const int fg = lane >> 4;
  auto readA = [&](int db, int mi, int kc) -> bf16x8 {
    const int row = wr * 128 + mi * 16 + fr;
    const int g = (kc * 4 + fg) ^ (row & 7);
    return *(const bf16x8*)(smem + db * 65536 + row * 128 + g * 16);
  };
  auto readB = [&](int db, int nj, int kc) -> bf16x8 {
    const int row = wc * 64 + nj * 16 + fr;
    const int g = (kc * 4 + fg) ^ (row & 7);
    return *(const bf16x8*)(smem + db * 65536 + 32768 + row * 128 + g * 16);
  };

  f32x4 acc[8][4];
#pragma unroll
  for (int i = 0; i < 8; i++)
#pragma unroll
    for (int j = 0; j < 4; j++) acc[i][j] = (f32x4){0.f, 0.f, 0.f, 0.f};

  stageA(0, 0, 0);
  stageA(0, 0, 1);
  stageB(0, 0, 0);
  stageB(0, 0, 1);
  stageB(1, 1, 0);
  stageB(1, 1, 1);
  asm volatile("s_waitcnt vmcnt(4)" ::: "memory");
  BAR();

  const int nt = K >> 6;
  const int niter = nt >> 1;

  for (int j = 0; j < niter; ++j) {
    const int t0 = 2 * j, t1 = 2 * j + 1;
    const bool more = (j + 1 < niter);
    bf16x8 a[4][2], b0[2][2], b1[2][2];

#pragma unroll
    for (int mi = 0; mi < 4; mi++) { a[mi][0] = readA(0, mi, 0); a[mi][1] = readA(0, mi, 1); }
#pragma unroll
    for (int nj = 0; nj < 2; nj++) { b0[nj][0] = readB(0, nj, 0); b0[nj][1] = readB(0, nj, 1); }
    stageA(1, t1, 0);
    asm volatile("s_waitcnt lgkmcnt(8)" ::: "memory");
    PH_OPEN();
    MFMA_QUAD(a, b0, 0, 0);
    PH_CLOSE();

#pragma unroll
    for (int nj = 0; nj < 2; nj++) { b1[nj][0] = readB(0, nj + 2, 0); b1[nj][1] = readB(0, nj + 2, 1); }
    stageA(1, t1, 1);
    PH_OPEN();
    MFMA_QUAD(a, b1, 0, 2);
    PH_CLOSE();

#pragma unroll
    for (int mi = 0; mi < 4; mi++) { a[mi][0] = readA(0, mi + 4, 0); a[mi][1] = readA(0, mi + 4, 1); }
    if (more) stageB(0, t0 + 2, 0);
    PH_OPEN();
    MFMA_QUAD(a, b0, 4, 0);
    PH_CLOSE();

    if (more) stageB(0, t0 + 2, 1);
    BAR();
    __builtin_amdgcn_s_setprio(1);
    MFMA_QUAD(a, b1, 4, 2);
    __builtin_amdgcn_s_setprio(0);
    if (more)
      asm volatile("s_waitcnt vmcnt(4)" ::: "memory");
    else
      asm volatile("s_waitcnt vmcnt(0)" ::: "memory");
    BAR();

#pragma unroll
    for (int mi = 0; mi < 4; mi++) { a[mi][0] = readA(1, mi, 0); a[mi][1] = readA(1, mi, 1); }
#pragma unroll
    for (int nj = 0; nj < 2; nj++) { b0[nj][0] = readB(1, nj, 0); b0[nj][1] = readB(1, nj, 1); }
    if (more) stageA(0, t0 + 2, 0);
    asm volatile("s_waitcnt lgkmcnt(8)" ::: "memory");
    PH_OPEN();
    MFMA_QUAD(a, b0, 0, 0);
    PH_CLOSE();

#pragma unroll
    for (int nj = 0; nj < 2; nj++) { b1[nj][0] = readB(1, nj + 2, 0); b1[nj][1] = readB(1, nj + 2, 1); }
    if (more) stageA(0, t0 + 2, 1);
    PH_OPEN();
    MFMA_QUAD(a, b1, 0, 2);
    PH_CLOSE();

#pragma unroll
    for (int mi = 0; mi < 4; mi++) { a[mi][0] = readA(1, mi + 4, 0); a[mi][1] = readA(1, mi + 4, 1); }
    if (more) stageB(1, t1 + 2, 0);
    PH_OPEN();
    MFMA_QUAD(a, b0, 4, 0);
    PH_CLOSE();

    if (more) stageB(1, t1 + 2, 1);
    BAR();
    __builtin_amdgcn_s_setprio(1);
    MFMA_QUAD(a, b1, 4, 2);
    __builtin_amdgcn_s_setprio(0);
    asm volatile("s_waitcnt vmcnt(4)" ::: "memory");
    BAR();
  }

  const int row0base = m0 + wr * 128 + fg * 4;

  // OUTMODE 1: LDS-transposed bf16 stores OUT[bcol][arow]
  {
    const int lcol = wc * 64 + fr;
    const int lrow0 = wr * 128 + fg * 4;
#pragma unroll
    for (int mi = 0; mi < 8; mi++) {
      const int lrow = lrow0 + mi * 16;
      float4 bw = make_float4(0.f, 0.f, 0.f, 0.f);
      if (HAS_BIAS) bw = *(const float4*)&bias[row0base + mi * 16];
#pragma unroll
      for (int nj = 0; nj < 4; nj++) {
        float v0 = acc[mi][nj][0] + bw.x;
        float v1 = acc[mi][nj][1] + bw.y;
        float v2 = acc[mi][nj][2] + bw.z;
        float v3 = acc[mi][nj][3] + bw.w;
        unsigned lo = (unsigned)f32_to_bf16(v0) | ((unsigned)f32_to_bf16(v1) << 16);
        unsigned hi = (unsigned)f32_to_bf16(v2) | ((unsigned)f32_to_bf16(v3) << 16);
        const int c = lcol + nj * 16;
        const int byte = c * 512 + ((((lrow >> 3) ^ (c & 7)) << 4) | ((lrow & 4) << 1));
        *(uint2*)(smem + byte) = make_uint2(lo, hi);
      }
    }
    __syncthreads();
    unsigned short* C = (unsigned short*)Cv + (size_t)bz * bsC;
    const int qh = wave * 2 + (lane >> 5);
    const int kl = (lane & 31) * 8;
#pragma unroll
    for (int p = 0; p < 16; p++) {
      const int ql = qh + p * 16;
      const int byte = ql * 512 + ((((kl >> 3) ^ (ql & 7)) << 4));
      uint4 vv = *(const uint4*)(smem + byte);
      *(uint4*)(C + (size_t)(n0 + ql) * M + m0 + kl) = vv;
    }
  }
}

// ---------------------------------------------------------------------------
extern "C" void kernel_launch(void* const* d_in, const int* in_sizes, int n_in,
                              void* d_out, int out_size, void* d_ws, size_t ws_size,
                              hipStream_t stream) {
  const float* q = (const float*)d_in[0];
  const float* k_ = (const float*)d_in[1];
  const float* v = (const float*)d_in[2];
  const int* msk = (const int*)d_in[3];
  const float* Wq = (const float*)d_in[4];
  const float* bq = (const float*)d_in[5];
  const float* Wk = (const float*)d_in[6];
  const float* Wv = (const float*)d_in[8];
  const float* bv = (const float*)d_in[9];
  const float* Wfc = (const float*)d_in[10];
  const float* bfc = (const float*)d_in[11];

  char* ws = (char*)d_ws;
  const size_t MB = 1u << 20;
  const size_t KB = 1u << 10;
  unsigned short* WkT = (unsigned short*)(ws + 0 * MB);
  unsigned short* WfcB = (unsigned short*)(ws + 2 * MB);
  unsigned short* WqT = (unsigned short*)(ws + 4 * MB);
  unsigned short* WvT = (unsigned short*)(ws + 6 * MB);
  unsigned short* Mt = (unsigned short*)(ws + 8 * MB);
  unsigned short* W2 = (unsigned short*)(ws + 10 * MB);
  float* partialT = (float*)(ws + 12 * MB);                 // 2 MB [32][16384]
  float* rowinv = (float*)(ws + 14 * MB);                   // 64 KB
  float* cv = (float*)(ws + 14 * MB + 64 * KB);
  float* g32 = (float*)(ws + 14 * MB + 128 * KB);
  float* w32 = (float*)(ws + 14 * MB + 192 * KB);           // 64 KB
  int* qidx = (int*)(ws + 14 * MB + 256 * KB);              // 64 KB
  int* midx = (int*)(ws + 14 * MB + 320 * KB);              // 64 KB
  int* cnts = (int*)(ws + 14 * MB + 384 * KB);              // 128 B
  float* cm = (float*)(ws + 14 * MB + 512 * KB);            // 32 KB
  unsigned short* Qc = (unsigned short*)(ws + 16 * MB);     // 32 MB
  unsigned short* xkB = (unsigned short*)(ws + 48 * MB);    // 32 MB
  unsigned short* vpT = (unsigned short*)(ws + 80 * MB);    // 32 MB [f][bs]
  unsigned short* xqC = (unsigned short*)(ws + 112 * MB);   // 32 MB compacted
  unsigned short* vB = (unsigned short*)(ws + 144 * MB);    // 32 MB
  unsigned short* E = (unsigned short*)(ws + 112 * MB);     // 64 MB (alias)

  const int NBS = Bb * S * D;

  auto conv = [&](const float* in, unsigned short* out, int n) {
    int n8 = n / 8;
    int blocks = (n8 + 255) / 256;
    if (blocks > 2048) blocks = 2048;
    conv_f32_bf16<<<dim3(blocks), dim3(256), 0, stream>>>(in, out, n8);
  };

  // ---- weight preprocessing
  tconv<<<dim3(16, 16, 1), dim3(256), 0, stream>>>(Wq, WqT, D, D);
  tconv<<<dim3(16, 16, 1), dim3(256), 0, stream>>>(Wk, WkT, D, D);
  conv(Wfc, WfcB, D * D);
  tconv<<<dim3(16, 16, 1), dim3(256), 0, stream>>>(Wv, WvT, D, D);
  gemm128<<<dim3(8, 8, 2), dim3(256), 0, stream>>>(
      WkT, WqT, Mt, D, D, D, (long long)D * D, (long long)D * D, (long long)D * D);
  cvec_kernel<<<dim3(1024), dim3(256), 0, stream>>>(Wfc, bv, bfc, cv);
  gvec_kernel<<<dim3(1024), dim3(256), 0, stream>>>(WkT, bq, g32);

  // ---- mask compaction
  mask_scan<<<dim3(8), dim3(256), 0, stream>>>(msk, qidx, midx, cnts);
  compact_q<<<dim3(16384), dim3(128), 0, stream>>>(q, qidx, cnts, xqC);

  const float invscale = 1.0f / 32.0f;

  // ---- Qc = xqC @ M : swapped (A=Mt, B=xqC) -> Qc[slot][f], exit on N
  gemm256<1, false, 1><<<dim3(64, 4, 1), dim3(512), 131072, stream>>>(
      Mt, xqC, nullptr, cnts, nullptr, nullptr, Qc, D, Bb * S, D, D, D,
      0, 0, 0, 1.0f);
  // ---- xkB = bf16(key_) + w32 in one pass
  conv_k_wvec<<<dim3(4096), dim3(256), 0, stream>>>(k_, g32, xkB, w32);
  // ---- vpT = (value @ W2^T)^T
  conv(v, vB, NBS);
  gemm256<1, false, 0><<<dim3(4, 64, 1), dim3(512), 131072, stream>>>(
      vB, W2, nullptr, nullptr, nullptr, nullptr, vpT, Bb * S, D, D, D, D,
      0, 0, 0, 1.0f);
  // ---- colmean of value' (+cv) for masked rows
  colmean_kernel<<<dim3(1024, 8), dim3(64), 0, stream>>>(vpT, cv, cm);
  // ---- E = exp(Qc.xk/32 + w32): 128x128 m97-structure, exit on query tiles
  gemm128c<3><<<dim3(16, 16, 8), dim3(256), 0, stream>>>(
      xkB, Qc, w32, nullptr, cnts, nullptr, partialT, E,
      D, 1024, 1024, 1024, (long long)S * D, (long long)S * D,
      (long long)S * S, invscale);
  // ---- rowinv
  rowinv_kernel<<<dim3(64), dim3(256), 0, stream>>>(partialT, rowinv);
  // ---- out(unmasked) = (P' @ value')*rowinv + cv: 128x128, exit on slot tiles
  gemm128c<6><<<dim3(8, 16, 8), dim3(256), 0, stream>>>(
      E, vpT, rowinv, cv, cnts, qidx, nullptr, d_out,
      D, 2048, 2048, Bb * S, (long long)S * S, (long long)S,
      (long long)S * D, 1.0f);
  // ---- out(masked) = colmean + cv
  fill_masked<<<dim3(16384), dim3(128), 0, stream>>>(midx, cnts, cm, (float*)d_out);
}